// Round 1
// baseline (282.695 us; speedup 1.0000x reference)
//
#include <hip/hip_runtime.h>
#include <math.h>

#define NPTS 32768          // b*h*w*d = 1*32*32*32
#define NE   2048
#define ED   16
#define TAU_INV 14.285714285714286f   // 1/0.07
#define ENT_INV 100.0f                 // 1/0.01
#define WAVES 8
#define CHUNK (NE / WAVES)             // 256

// output layout (floats, concatenated in return order)
#define OFF_SOFT 0
#define OFF_LOSS 524288
#define OFF_HARD 524289
#define OFF_IDX  1048577

// workspace layout (floats)
#define WS_EMB  0        // 2048*16 normalized embedding
#define WS_PSUM 32768    // 2048 column sums of ent-probs
#define WS_SSUM 34816    // 1 scalar: sum of per-row sample-entropy terms

__global__ __launch_bounds__(256) void vq_prep(const float* __restrict__ emb,
                                               float* __restrict__ ws) {
    int t = blockIdx.x * 256 + threadIdx.x;
    if (t < NE) {
        float v[ED]; float s = 0.f;
        #pragma unroll
        for (int c = 0; c < ED; ++c) { v[c] = emb[t * ED + c]; s += v[c] * v[c]; }
        float inv = 1.0f / fmaxf(sqrtf(s), 1e-12f);
        #pragma unroll
        for (int c = 0; c < ED; ++c) ws[WS_EMB + t * ED + c] = v[c] * inv;
        ws[WS_PSUM + t] = 0.f;
    }
    if (t == 0) ws[WS_SSUM] = 0.f;
}

__global__ __launch_bounds__(WAVES * 64) void vq_main(const float* __restrict__ z,
                                                      const float* __restrict__ embN,
                                                      float* __restrict__ psum,
                                                      float* __restrict__ ssum,
                                                      float* __restrict__ out) {
    const int lane = threadIdx.x & 63;
    const int w    = threadIdx.x >> 6;
    const int n    = blockIdx.x * 64 + lane;

    __shared__ float sm[WAVES][64];
    __shared__ float ss1[WAVES][64];
    __shared__ float ss2[WAVES][64];
    __shared__ float sst[WAVES][64];
    __shared__ int   sam[WAVES][64];
    __shared__ float svec[WAVES][64][ED];
    __shared__ float pblock[NE];

    // ---- load z row (channel-strided) and l2-normalize
    float zn[ED]; float s = 0.f;
    #pragma unroll
    for (int c = 0; c < ED; ++c) { float v = z[c * NPTS + n]; zn[c] = v; s += v * v; }
    float rinv = 1.0f / fmaxf(sqrtf(s), 1e-12f);
    #pragma unroll
    for (int c = 0; c < ED; ++c) zn[c] *= rinv;

    const int kbase = w * CHUNK;

    // ---- pass 1: online max / argmax / S1,S2 (ent-temp) / St (tau) over this wave's chunk
    float m = -1e30f; int am = kbase;
    float S1 = 0.f, S2 = 0.f, St = 0.f;
    for (int i = 0; i < CHUNK; ++i) {
        int k  = kbase + i;
        int ku = __builtin_amdgcn_readfirstlane(k);   // wave-uniform -> scalar/broadcast loads
        const float* e = embN + ku * ED;
        float l = 0.f;
        #pragma unroll
        for (int c = 0; c < ED; ++c) l = fmaf(zn[c], e[c], l);
        if (l > m) {
            // new max: rescale running sums (d <= 0, finite since m init finite)
            float d  = m - l;
            float re = expf(d * ENT_INV);
            float rt = expf(d * TAU_INV);
            S2 = re * (S2 + d * ENT_INV * S1);
            S1 = S1 * re + 1.0f;
            St = St * rt + 1.0f;
            m = l; am = k;
        } else {
            float de = (l - m) * ENT_INV;
            float ee = expf(de);
            S1 += ee;
            S2 += de * ee;
            St += expf((l - m) * TAU_INV);
        }
    }
    sm[w][lane] = m; ss1[w][lane] = S1; ss2[w][lane] = S2; sst[w][lane] = St; sam[w][lane] = am;
    __syncthreads();

    // ---- flash-combine the 8 wave-chunks (every thread, for its own row)
    float M = sm[0][lane]; int AM = sam[0][lane];
    #pragma unroll
    for (int j = 1; j < WAVES; ++j) {
        float mj = sm[j][lane];
        if (mj > M) { M = mj; AM = sam[j][lane]; }   // strict > keeps first (lowest k)
    }
    float S1t = 0.f, S2t = 0.f, Stt = 0.f;
    #pragma unroll
    for (int j = 0; j < WAVES; ++j) {
        float d  = sm[j][lane] - M;                   // <= 0
        float re = expf(d * ENT_INV);
        float rt = expf(d * TAU_INV);
        S1t += ss1[j][lane] * re;
        S2t += (ss2[j][lane] + d * ENT_INV * ss1[j][lane]) * re;
        Stt += sst[j][lane] * rt;
    }
    float invS1 = 1.0f / S1t;

    // ---- pass 2: z_q_soft partials + avg_probs column accumulation
    float vec[ED];
    #pragma unroll
    for (int c = 0; c < ED; ++c) vec[c] = 0.f;
    for (int i = 0; i < CHUNK; ++i) {
        int k  = kbase + i;
        int ku = __builtin_amdgcn_readfirstlane(k);
        const float* e = embN + ku * ED;
        float l = 0.f;
        #pragma unroll
        for (int c = 0; c < ED; ++c) l = fmaf(zn[c], e[c], l);
        float et = expf((l - M) * TAU_INV);
        #pragma unroll
        for (int c = 0; c < ED; ++c) vec[c] = fmaf(et, e[c], vec[c]);
        float p = expf((l - M) * ENT_INV) * invS1;
        // sum p over the 64 rows of this block (butterfly)
        #pragma unroll
        for (int off = 32; off > 0; off >>= 1) p += __shfl_xor(p, off, 64);
        if (lane == 0) pblock[k] = p;                 // each k written exactly once per block
    }
    #pragma unroll
    for (int c = 0; c < ED; ++c) svec[w][lane][c] = vec[c];
    __syncthreads();

    // ---- epilogue (wave 0): combine z_q_soft, write outputs, sample-entropy
    if (w == 0) {
        float invSt = 1.0f / Stt;
        #pragma unroll
        for (int c = 0; c < ED; ++c) {
            float v = 0.f;
            #pragma unroll
            for (int j = 0; j < WAVES; ++j) v += svec[j][lane][c];
            out[OFF_SOFT + c * NPTS + n] = v * invSt;
        }
        out[OFF_IDX + n] = (float)AM;                 // indices as float (out buffer is f32)
        #pragma unroll
        for (int c = 0; c < ED; ++c)
            out[OFF_HARD + c * NPTS + n] = embN[AM * ED + c];
        // per-row: sum_k p*logp = S2/S1 - ln(S1)  ->  sample term = ln(S1) - S2/S1
        float r = logf(S1t) - S2t * invS1;
        #pragma unroll
        for (int off = 32; off > 0; off >>= 1) r += __shfl_xor(r, off, 64);
        if (lane == 0) atomicAdd(ssum, r);
    }
    __syncthreads();

    // ---- flush this block's avg_probs partials
    for (int k = threadIdx.x; k < NE; k += WAVES * 64) atomicAdd(&psum[k], pblock[k]);
}

__global__ __launch_bounds__(256) void vq_finalize(const float* __restrict__ ws,
                                                   float* __restrict__ out) {
    __shared__ float red[4];
    float a = 0.f;
    for (int k = threadIdx.x; k < NE; k += 256) {
        float avg = ws[WS_PSUM + k] * (1.0f / 32768.0f);
        a += avg * logf(avg + 1e-6f);                 // = -avg_entropy contribution
    }
    #pragma unroll
    for (int off = 32; off > 0; off >>= 1) a += __shfl_xor(a, off, 64);
    if ((threadIdx.x & 63) == 0) red[threadIdx.x >> 6] = a;
    __syncthreads();
    if (threadIdx.x == 0) {
        float A = red[0] + red[1] + red[2] + red[3];  // A = -avg_entropy
        float sample = ws[WS_SSUM] * (1.0f / 32768.0f);
        out[OFF_LOSS] = 0.01f * (sample + A);         // ratio * (sample_ent - avg_ent)
    }
}

extern "C" void kernel_launch(void* const* d_in, const int* in_sizes, int n_in,
                              void* d_out, int out_size, void* d_ws, size_t ws_size,
                              hipStream_t stream) {
    const float* z   = (const float*)d_in[0];
    const float* emb = (const float*)d_in[1];
    float* out = (float*)d_out;
    float* ws  = (float*)d_ws;   // needs 34817 floats (~136 KB)

    vq_prep<<<(NE + 255) / 256, 256, 0, stream>>>(emb, ws);
    vq_main<<<NPTS / 64, WAVES * 64, 0, stream>>>(z, ws + WS_EMB, ws + WS_PSUM,
                                                  ws + WS_SSUM, out);
    vq_finalize<<<1, 256, 0, stream>>>(ws, out);
}

// Round 2
// 208.675 us; speedup vs baseline: 1.3547x; 1.3547x over previous
//
#include <hip/hip_runtime.h>
#include <math.h>

#define NPTS 32768          // b*h*w*d = 1*32*32*32
#define NE   2048
#define ED   16
#define WAVES 8
#define CHUNK (NE / WAVES)             // 256

// exp2-domain temperature constants (exp(x*T) == exp2(x*T*log2e))
#define KT2 20.60992915555662f         // (1/0.07) * log2(e)
#define KE2 144.26950408889634f        // 100 * log2(e)  (== 7*KT2 exactly in R)

// output layout (floats, concatenated in return order)
#define OFF_SOFT 0
#define OFF_LOSS 524288
#define OFF_HARD 524289
#define OFF_IDX  1048577

// workspace layout (floats)
#define WS_EMB  0        // 2048*16 normalized embedding
#define WS_PSUM 32768    // 2048 column sums of ent-probs
#define WS_SSUM 34816    // 1 scalar: sum of per-row sample-entropy terms

__device__ __forceinline__ float fexp2(float x) {
#if __has_builtin(__builtin_amdgcn_exp2f)
    return __builtin_amdgcn_exp2f(x);   // v_exp_f32
#else
    float r; asm("v_exp_f32 %0, %1" : "=v"(r) : "v"(x)); return r;
#endif
}

__global__ __launch_bounds__(256) void vq_prep(const float* __restrict__ emb,
                                               float* __restrict__ ws) {
    int t = blockIdx.x * 256 + threadIdx.x;
    if (t < NE) {
        float v[ED]; float s = 0.f;
        #pragma unroll
        for (int c = 0; c < ED; ++c) { v[c] = emb[t * ED + c]; s += v[c] * v[c]; }
        float inv = 1.0f / fmaxf(sqrtf(s), 1e-12f);
        #pragma unroll
        for (int c = 0; c < ED; ++c) ws[WS_EMB + t * ED + c] = v[c] * inv;
        ws[WS_PSUM + t] = 0.f;
    }
    if (t == 0) ws[WS_SSUM] = 0.f;
}

__global__ __launch_bounds__(WAVES * 64) void vq_main(const float* __restrict__ z,
                                                      const float* __restrict__ embN,
                                                      float* __restrict__ psum,
                                                      float* __restrict__ ssum,
                                                      float* __restrict__ out) {
    const int lane = threadIdx.x & 63;
    const int w    = threadIdx.x >> 6;
    const int n    = blockIdx.x * 64 + lane;

    __shared__ float sm[WAVES][64];
    __shared__ float ss1[WAVES][64];
    __shared__ float ss2[WAVES][64];
    __shared__ float sst[WAVES][64];
    __shared__ int   sam[WAVES][64];
    __shared__ float svec[WAVES][64][ED];
    __shared__ float pblock[NE];

    // ---- load z row (channel-strided) and l2-normalize
    float zn[ED]; float s = 0.f;
    #pragma unroll
    for (int c = 0; c < ED; ++c) { float v = z[c * NPTS + n]; zn[c] = v; s += v * v; }
    float rinv = 1.0f / fmaxf(sqrtf(s), 1e-12f);
    #pragma unroll
    for (int c = 0; c < ED; ++c) zn[c] *= rinv;

    const int kbase = w * CHUNK;

    // ---- pass 1: online max / argmax / S1,S2 (ent-temp only) over this wave's chunk
    float m = -2.0f; int am = kbase;          // cosines are in [-1,1]
    float S1 = 0.f, S2 = 0.f;
    for (int i = 0; i < CHUNK; ++i) {
        int k  = kbase + i;
        int ku = __builtin_amdgcn_readfirstlane(k);   // wave-uniform -> scalar loads
        const float* e = embN + ku * ED;
        float l0 = 0.f, l1 = 0.f, l2 = 0.f, l3 = 0.f;
        #pragma unroll
        for (int c = 0; c < ED; c += 4) {
            l0 = fmaf(zn[c + 0], e[c + 0], l0);
            l1 = fmaf(zn[c + 1], e[c + 1], l1);
            l2 = fmaf(zn[c + 2], e[c + 2], l2);
            l3 = fmaf(zn[c + 3], e[c + 3], l3);
        }
        float l = (l0 + l1) + (l2 + l3);
        if (l > m) {
            float d  = m - l;                         // <= 0
            float re = fexp2(d * KE2);
            S2 = re * fmaf(d * 100.f, S1, S2);
            S1 = fmaf(S1, re, 1.0f);
            m = l; am = k;
        } else {
            float d  = l - m;
            float ee = fexp2(d * KE2);
            S1 += ee;
            S2 = fmaf(d * 100.f, ee, S2);
        }
    }
    sm[w][lane] = m; ss1[w][lane] = S1; ss2[w][lane] = S2; sam[w][lane] = am;
    __syncthreads();

    // ---- flash-combine the 8 wave-chunks (every thread, for its own row)
    float M = sm[0][lane]; int AM = sam[0][lane];
    #pragma unroll
    for (int j = 1; j < WAVES; ++j) {
        float mj = sm[j][lane];
        if (mj > M) { M = mj; AM = sam[j][lane]; }   // strict > keeps first (lowest k)
    }
    float S1t = 0.f, S2t = 0.f;
    #pragma unroll
    for (int j = 0; j < WAVES; ++j) {
        float d  = sm[j][lane] - M;                   // <= 0
        float re = fexp2(d * KE2);
        S1t += ss1[j][lane] * re;
        S2t += fmaf(d * 100.f, ss1[j][lane], ss2[j][lane]) * re;
    }
    float invS1 = 1.0f / S1t;

    // ---- pass 2: z_q_soft partials (unnormalized), tau-sum, avg_probs columns
    float vec[ED];
    #pragma unroll
    for (int c = 0; c < ED; ++c) vec[c] = 0.f;
    float St = 0.f;
    for (int i = 0; i < CHUNK; ++i) {
        int k  = kbase + i;
        int ku = __builtin_amdgcn_readfirstlane(k);
        const float* e = embN + ku * ED;
        float l0 = 0.f, l1 = 0.f, l2 = 0.f, l3 = 0.f;
        #pragma unroll
        for (int c = 0; c < ED; c += 4) {
            l0 = fmaf(zn[c + 0], e[c + 0], l0);
            l1 = fmaf(zn[c + 1], e[c + 1], l1);
            l2 = fmaf(zn[c + 2], e[c + 2], l2);
            l3 = fmaf(zn[c + 3], e[c + 3], l3);
        }
        float a  = ((l0 + l1) + (l2 + l3)) - M;       // <= 0
        float rt = fexp2(a * KT2);                    // tau prob (unnormalized)
        St += rt;
        float p = fexp2(a * KE2) * invS1;             // ent prob (normalized)
        #pragma unroll
        for (int c = 0; c < ED; ++c) vec[c] = fmaf(rt, e[c], vec[c]);
        // sum p over the 64 rows of this block (butterfly)
        #pragma unroll
        for (int off = 32; off > 0; off >>= 1) p += __shfl_xor(p, off, 64);
        if (lane == 0) pblock[k] = p;                 // each k written exactly once per block
    }
    #pragma unroll
    for (int c = 0; c < ED; ++c) svec[w][lane][c] = vec[c];
    sst[w][lane] = St;
    __syncthreads();

    // ---- epilogue (wave 0): combine z_q_soft + tau-denominator, write outputs
    if (w == 0) {
        float Stt = 0.f;
        #pragma unroll
        for (int j = 0; j < WAVES; ++j) Stt += sst[j][lane];
        float invSt = 1.0f / Stt;
        #pragma unroll
        for (int c = 0; c < ED; ++c) {
            float v = 0.f;
            #pragma unroll
            for (int j = 0; j < WAVES; ++j) v += svec[j][lane][c];
            out[OFF_SOFT + c * NPTS + n] = v * invSt;
        }
        out[OFF_IDX + n] = (float)AM;
        #pragma unroll
        for (int c = 0; c < ED; ++c)
            out[OFF_HARD + c * NPTS + n] = embN[AM * ED + c];
        // per-row: sum_k p*logp = S2/S1 - ln(S1)  ->  sample term = ln(S1) - S2/S1
        float r = logf(S1t) - S2t * invS1;
        #pragma unroll
        for (int off = 32; off > 0; off >>= 1) r += __shfl_xor(r, off, 64);
        if (lane == 0) atomicAdd(ssum, r);
    }
    __syncthreads();

    // ---- flush this block's avg_probs partials
    for (int k = threadIdx.x; k < NE; k += WAVES * 64) atomicAdd(&psum[k], pblock[k]);
}

__global__ __launch_bounds__(256) void vq_finalize(const float* __restrict__ ws,
                                                   float* __restrict__ out) {
    __shared__ float red[4];
    float a = 0.f;
    for (int k = threadIdx.x; k < NE; k += 256) {
        float avg = ws[WS_PSUM + k] * (1.0f / 32768.0f);
        a += avg * logf(avg + 1e-6f);                 // = -avg_entropy contribution
    }
    #pragma unroll
    for (int off = 32; off > 0; off >>= 1) a += __shfl_xor(a, off, 64);
    if ((threadIdx.x & 63) == 0) red[threadIdx.x >> 6] = a;
    __syncthreads();
    if (threadIdx.x == 0) {
        float A = red[0] + red[1] + red[2] + red[3];  // A = -avg_entropy
        float sample = ws[WS_SSUM] * (1.0f / 32768.0f);
        out[OFF_LOSS] = 0.01f * (sample + A);         // ratio * (sample_ent - avg_ent)
    }
}

extern "C" void kernel_launch(void* const* d_in, const int* in_sizes, int n_in,
                              void* d_out, int out_size, void* d_ws, size_t ws_size,
                              hipStream_t stream) {
    const float* z   = (const float*)d_in[0];
    const float* emb = (const float*)d_in[1];
    float* out = (float*)d_out;
    float* ws  = (float*)d_ws;   // needs 34817 floats (~136 KB)

    vq_prep<<<(NE + 255) / 256, 256, 0, stream>>>(emb, ws);
    vq_main<<<NPTS / 64, WAVES * 64, 0, stream>>>(z, ws + WS_EMB, ws + WS_PSUM,
                                                  ws + WS_SSUM, out);
    vq_finalize<<<1, 256, 0, stream>>>(ws, out);
}

// Round 3
// 179.653 us; speedup vs baseline: 1.5736x; 1.1615x over previous
//
#include <hip/hip_runtime.h>
#include <math.h>

#define NPTS 32768          // b*h*w*d = 1*32*32*32
#define NE   2048
#define ED   16
#define WAVES 16
#define CHUNK (NE / WAVES)   // 128
#define HALFC (CHUNK / 2)    // 64

// exp2-domain temperature constants (exp(x*T) == exp2(x*T*log2e))
#define KT2 20.60992915555662f          // (1/0.07) * log2(e)
#define KE2 144.26950408889634f         // 100 * log2(e)
#define LN2 0.69314718055994531f

// output layout (floats, concatenated in return order)
#define OFF_SOFT 0
#define OFF_LOSS 524288
#define OFF_HARD 524289
#define OFF_IDX  1048577

// workspace layout (floats)
#define WS_EMB  0        // 2048*16 normalized embedding
#define WS_PSUM 32768    // 2048 column sums of ent-probs
#define WS_SSUM 34816    // 1 scalar: sum of per-row sample-entropy terms

__device__ __forceinline__ float fexp2(float x) {
#if __has_builtin(__builtin_amdgcn_exp2f)
    return __builtin_amdgcn_exp2f(x);   // v_exp_f32
#else
    float r; asm("v_exp_f32 %0, %1" : "=v"(r) : "v"(x)); return r;
#endif
}

__global__ __launch_bounds__(256) void vq_prep(const float* __restrict__ emb,
                                               float* __restrict__ ws) {
    int t = blockIdx.x * 256 + threadIdx.x;
    if (t < NE) {
        float v[ED]; float s = 0.f;
        #pragma unroll
        for (int c = 0; c < ED; ++c) { v[c] = emb[t * ED + c]; s += v[c] * v[c]; }
        float inv = 1.0f / fmaxf(sqrtf(s), 1e-12f);
        #pragma unroll
        for (int c = 0; c < ED; ++c) ws[WS_EMB + t * ED + c] = v[c] * inv;
        ws[WS_PSUM + t] = 0.f;
    }
    if (t == 0) ws[WS_SSUM] = 0.f;
}

__global__ __launch_bounds__(1024, 6) void vq_main(const float* __restrict__ z,
                                                   const float* __restrict__ embN,
                                                   float* __restrict__ psum,
                                                   float* __restrict__ ssum,
                                                   float* __restrict__ out) {
    const int lane = threadIdx.x & 63;
    const int w    = threadIdx.x >> 6;
    const int n    = blockIdx.x * 64 + lane;

    __shared__ float sm [WAVES][64];
    __shared__ float ss1[WAVES][64];
    __shared__ int   sam[WAVES][64];
    __shared__ float sst[WAVES][64];
    __shared__ float sr [WAVES][64];
    __shared__ float svec[WAVES / 2][64][ED + 1];   // +1 pad: kill 32-way bank conflict

    // ---- load z row (channel-strided) and l2-normalize
    float zn[ED]; float s = 0.f;
    #pragma unroll
    for (int c = 0; c < ED; ++c) { float v = z[c * NPTS + n]; zn[c] = v; s += v * v; }
    float rinv = 1.0f / fmaxf(sqrtf(s), 1e-12f);
    #pragma unroll
    for (int c = 0; c < ED; ++c) zn[c] *= rinv;

    const int kbase = w * CHUNK;

    // ---- pass 1: branchless online max/argmax/S1, two independent chains
    float m0 = -2.f, m1 = -2.f, s10 = 0.f, s11 = 0.f;   // cosines in [-1,1]
    int am0 = kbase, am1 = kbase + HALFC;
    for (int i = 0; i < HALFC; ++i) {
        int ka = __builtin_amdgcn_readfirstlane(kbase + i);
        int kb = __builtin_amdgcn_readfirstlane(kbase + HALFC + i);
        const float* ea = embN + ka * ED;
        const float* eb = embN + kb * ED;
        float a0 = 0.f, a1 = 0.f, a2 = 0.f, a3 = 0.f;
        float b0 = 0.f, b1 = 0.f, b2 = 0.f, b3 = 0.f;
        #pragma unroll
        for (int c = 0; c < ED; c += 4) {
            a0 = fmaf(zn[c + 0], ea[c + 0], a0);
            a1 = fmaf(zn[c + 1], ea[c + 1], a1);
            a2 = fmaf(zn[c + 2], ea[c + 2], a2);
            a3 = fmaf(zn[c + 3], ea[c + 3], a3);
            b0 = fmaf(zn[c + 0], eb[c + 0], b0);
            b1 = fmaf(zn[c + 1], eb[c + 1], b1);
            b2 = fmaf(zn[c + 2], eb[c + 2], b2);
            b3 = fmaf(zn[c + 3], eb[c + 3], b3);
        }
        float la = (a0 + a1) + (a2 + a3);
        float lb = (b0 + b1) + (b2 + b3);
        // chain 0: S1 = max? S1*e+1 : S1+e, with e = exp2(-|l-m|*K)
        float e0 = fexp2(-fabsf(la - m0) * KE2);
        bool  g0 = la > m0;
        am0 = g0 ? (kbase + i) : am0;
        m0  = fmaxf(m0, la);
        s10 = g0 ? fmaf(s10, e0, 1.0f) : (s10 + e0);
        // chain 1
        float e1 = fexp2(-fabsf(lb - m1) * KE2);
        bool  g1 = lb > m1;
        am1 = g1 ? (kbase + HALFC + i) : am1;
        m1  = fmaxf(m1, lb);
        s11 = g1 ? fmaf(s11, e1, 1.0f) : (s11 + e1);
    }
    {   // merge chains; chain0 owns lower k, so strict > keeps first max
        float em = fexp2(-fabsf(m1 - m0) * KE2);
        bool  g  = m1 > m0;
        sam[w][lane] = g ? am1 : am0;
        sm [w][lane] = fmaxf(m0, m1);
        ss1[w][lane] = g ? fmaf(s10, em, s11) : fmaf(s11, em, s10);
    }
    __syncthreads();

    // ---- flash-combine the 16 wave-chunks (every thread, own row)
    float M = sm[0][lane]; int AM = sam[0][lane];
    #pragma unroll
    for (int j = 1; j < WAVES; ++j) {
        float mj = sm[j][lane];
        if (mj > M) { M = mj; AM = sam[j][lane]; }    // ascending k: > keeps first
    }
    float S1t = 0.f;
    #pragma unroll
    for (int j = 0; j < WAVES; ++j)
        S1t += ss1[j][lane] * fexp2((sm[j][lane] - M) * KE2);
    float invS1 = 1.0f / S1t;

    // ---- pass 2: z_q_soft partials, tau-sum, entropy dot, avg_probs columns
    float vec[ED];
    #pragma unroll
    for (int c = 0; c < ED; ++c) vec[c] = 0.f;
    float St = 0.f, r = 0.f;
    for (int i = 0; i < CHUNK; i += 4) {
        float pv[4];
        #pragma unroll
        for (int j = 0; j < 4; ++j) {
            int ku = __builtin_amdgcn_readfirstlane(kbase + i + j);
            const float* e = embN + ku * ED;
            float l0 = 0.f, l1 = 0.f, l2 = 0.f, l3 = 0.f;
            #pragma unroll
            for (int c = 0; c < ED; c += 4) {
                l0 = fmaf(zn[c + 0], e[c + 0], l0);
                l1 = fmaf(zn[c + 1], e[c + 1], l1);
                l2 = fmaf(zn[c + 2], e[c + 2], l2);
                l3 = fmaf(zn[c + 3], e[c + 3], l3);
            }
            float a  = ((l0 + l1) + (l2 + l3)) - M;   // <= 0 (same dot order as pass 1)
            float aK = a * KE2;
            float rt = fexp2(a * KT2);                // tau weight (unnormalized)
            float pe = fexp2(aK);                     // ent weight
            float p  = pe * invS1;                    // normalized ent prob
            St += rt;
            r   = fmaf(p, aK, r);                     // Σ p·a·100·log2e
            #pragma unroll
            for (int c = 0; c < ED; ++c) vec[c] = fmaf(rt, e[c], vec[c]);
            pv[j] = p;
        }
        // reduce pv[0..3] across 64 lanes: array-halving butterfly (o=2,1),
        // then single-value butterfly (o=4,8,16,32). lane l ends with k-offset l&3.
        bool u2 = (lane & 2) != 0, u1 = (lane & 1) != 0;
        float t0 = (u2 ? pv[2] : pv[0]) + __shfl_xor(u2 ? pv[0] : pv[2], 2, 64);
        float t1 = (u2 ? pv[3] : pv[1]) + __shfl_xor(u2 ? pv[1] : pv[3], 2, 64);
        float v  = (u1 ? t1 : t0) + __shfl_xor(u1 ? t0 : t1, 1, 64);
        v += __shfl_xor(v, 4, 64);
        v += __shfl_xor(v, 8, 64);
        v += __shfl_xor(v, 16, 64);
        v += __shfl_xor(v, 32, 64);
        if (lane < 4) atomicAdd(&psum[kbase + i + lane], v);
    }

    sst[w][lane] = St; sr[w][lane] = r;
    if (w >= 8) {
        #pragma unroll
        for (int c = 0; c < ED; ++c) svec[w - 8][lane][c] = vec[c];
    }
    __syncthreads();
    if (w < 8) {
        #pragma unroll
        for (int c = 0; c < ED; ++c) {
            float t = vec[c] + svec[w][lane][c];
            svec[w][lane][c] = t;
        }
    }
    __syncthreads();

    // ---- epilogue (wave 0): combine + write outputs + sample-entropy
    if (w == 0) {
        float Stt = 0.f;
        #pragma unroll
        for (int j = 0; j < WAVES; ++j) Stt += sst[j][lane];
        float invSt = 1.0f / Stt;
        #pragma unroll
        for (int c = 0; c < ED; ++c) {
            float v = 0.f;
            #pragma unroll
            for (int j = 0; j < 8; ++j) v += svec[j][lane][c];
            out[OFF_SOFT + c * NPTS + n] = v * invSt;
        }
        out[OFF_IDX + n] = (float)AM;
        #pragma unroll
        for (int c = 0; c < ED; ++c)
            out[OFF_HARD + c * NPTS + n] = embN[AM * ED + c];
        // per-row sample term = ln(S1) - ln2 * Σ p·aK
        float rr = 0.f;
        #pragma unroll
        for (int j = 0; j < WAVES; ++j) rr += sr[j][lane];
        float row = logf(S1t) - LN2 * rr;
        #pragma unroll
        for (int off = 32; off > 0; off >>= 1) row += __shfl_xor(row, off, 64);
        if (lane == 0) atomicAdd(ssum, row);
    }
}

__global__ __launch_bounds__(256) void vq_finalize(const float* __restrict__ ws,
                                                   float* __restrict__ out) {
    __shared__ float red[4];
    float a = 0.f;
    for (int k = threadIdx.x; k < NE; k += 256) {
        float avg = ws[WS_PSUM + k] * (1.0f / 32768.0f);
        a += avg * logf(avg + 1e-6f);                 // = -avg_entropy contribution
    }
    #pragma unroll
    for (int off = 32; off > 0; off >>= 1) a += __shfl_xor(a, off, 64);
    if ((threadIdx.x & 63) == 0) red[threadIdx.x >> 6] = a;
    __syncthreads();
    if (threadIdx.x == 0) {
        float A = red[0] + red[1] + red[2] + red[3];  // A = -avg_entropy
        float sample = ws[WS_SSUM] * (1.0f / 32768.0f);
        out[OFF_LOSS] = 0.01f * (sample + A);         // ratio * (sample_ent - avg_ent)
    }
}

extern "C" void kernel_launch(void* const* d_in, const int* in_sizes, int n_in,
                              void* d_out, int out_size, void* d_ws, size_t ws_size,
                              hipStream_t stream) {
    const float* z   = (const float*)d_in[0];
    const float* emb = (const float*)d_in[1];
    float* out = (float*)d_out;
    float* ws  = (float*)d_ws;   // needs 34817 floats (~136 KB)

    vq_prep<<<(NE + 255) / 256, 256, 0, stream>>>(emb, ws);
    vq_main<<<NPTS / 64, WAVES * 64, 0, stream>>>(z, ws + WS_EMB, ws + WS_PSUM,
                                                  ws + WS_SSUM, out);
    vq_finalize<<<1, 256, 0, stream>>>(ws, out);
}

// Round 8
// 175.239 us; speedup vs baseline: 1.6132x; 1.0252x over previous
//
#include <hip/hip_runtime.h>
#include <math.h>

typedef float f32x2 __attribute__((ext_vector_type(2)));

#define NPTS 32768          // b*h*w*d = 1*32*32*32
#define NE   2048
#define ED   16
#define WAVES 16
#define CHUNK (NE / WAVES)   // 128
#define HALFC (CHUNK / 2)    // 64

// exp2-domain temperature constants (exp(x*T) == exp2(x*T*log2e))
#define KT2 20.60992915555662f          // (1/0.07) * log2(e)
#define KE2 144.26950408889634f         // 100 * log2(e)
#define LN2 0.69314718055994531f

// output layout (floats, concatenated in return order)
#define OFF_SOFT 0
#define OFF_LOSS 524288
#define OFF_HARD 524289
#define OFF_IDX  1048577

// workspace layout (floats)
#define WS_EMB  0        // 2048*16 normalized embedding
#define WS_PSUM 32768    // 2048 column sums of ent-probs
#define WS_SSUM 34816    // 1 scalar

__device__ __forceinline__ float fexp2(float x) {
#if __has_builtin(__builtin_amdgcn_exp2f)
    return __builtin_amdgcn_exp2f(x);   // v_exp_f32
#else
    float r; asm("v_exp_f32 %0, %1" : "=v"(r) : "v"(x)); return r;
#endif
}

// dot over 16 channels with v_pk_fma_f32; accumulator partition identical to
// the scalar l0..l3 version (a.x=l0 a.y=l1 b.x=l2 b.y=l3, final (l0+l1)+(l2+l3))
// -> bit-identical logits vs the round-3 passing kernel (argmax unchanged).
__device__ __forceinline__ float dot16(const f32x2 zn2[8], const f32x2* __restrict__ e) {
    f32x2 a = zn2[0] * e[0];
    f32x2 b = zn2[1] * e[1];
    a = __builtin_elementwise_fma(zn2[2], e[2], a);
    b = __builtin_elementwise_fma(zn2[3], e[3], b);
    a = __builtin_elementwise_fma(zn2[4], e[4], a);
    b = __builtin_elementwise_fma(zn2[5], e[5], b);
    a = __builtin_elementwise_fma(zn2[6], e[6], a);
    b = __builtin_elementwise_fma(zn2[7], e[7], b);
    return (a.x + a.y) + (b.x + b.y);
}

__global__ __launch_bounds__(256) void vq_prep(const float* __restrict__ emb,
                                               float* __restrict__ ws) {
    int t = blockIdx.x * 256 + threadIdx.x;
    if (t < NE) {
        float v[ED]; float s = 0.f;
        #pragma unroll
        for (int c = 0; c < ED; ++c) { v[c] = emb[t * ED + c]; s += v[c] * v[c]; }
        float inv = 1.0f / fmaxf(sqrtf(s), 1e-12f);
        #pragma unroll
        for (int c = 0; c < ED; ++c) ws[WS_EMB + t * ED + c] = v[c] * inv;
        ws[WS_PSUM + t] = 0.f;
    }
    if (t == 0) ws[WS_SSUM] = 0.f;
}

__global__ __launch_bounds__(1024, 6) void vq_main(const float* __restrict__ z,
                                                   const float* __restrict__ embN,
                                                   float* __restrict__ psum,
                                                   float* __restrict__ ssum,
                                                   float* __restrict__ out) {
    const int lane = threadIdx.x & 63;
    const int w    = threadIdx.x >> 6;
    const int n    = blockIdx.x * 64 + lane;

    __shared__ float sm [WAVES][64];
    __shared__ float ss1[WAVES][64];
    __shared__ int   sam[WAVES][64];
    __shared__ float sst[WAVES][64];
    __shared__ float sr [WAVES][64];
    __shared__ float svec[WAVES / 2][64][ED + 1];   // +1 pad: conflict-free

    // ---- load z row (channel-strided) and l2-normalize.
    // Norm accumulation kept scalar-sequential: bit-identical to round-3.
    float zn[ED]; float s = 0.f;
    #pragma unroll
    for (int c = 0; c < ED; ++c) { float v = z[c * NPTS + n]; zn[c] = v; s += v * v; }
    float rinv = 1.0f / fmaxf(sqrtf(s), 1e-12f);
    f32x2 zn2[8];
    #pragma unroll
    for (int q = 0; q < 8; ++q) zn2[q] = f32x2{zn[2 * q] * rinv, zn[2 * q + 1] * rinv};

    const int kbase = w * CHUNK;
    const f32x2* __restrict__ E = (const f32x2*)embN;   // 8 f32x2 per codeword

    // ---- pass 1: branchless online max/argmax/S1, two independent chains
    float m0 = -2.f, m1 = -2.f, s10 = 0.f, s11 = 0.f;   // cosines in [-1,1]
    int am0 = kbase, am1 = kbase + HALFC;
    for (int i = 0; i < HALFC; ++i) {
        int ka = __builtin_amdgcn_readfirstlane(kbase + i);
        int kb = __builtin_amdgcn_readfirstlane(kbase + HALFC + i);
        float la = dot16(zn2, E + (size_t)ka * 8);
        float lb = dot16(zn2, E + (size_t)kb * 8);
        // chain 0: S1 = max? S1*e+1 : S1+e, with e = exp2(-|l-m|*K)
        float e0 = fexp2(-fabsf(la - m0) * KE2);
        bool  g0 = la > m0;
        am0 = g0 ? (kbase + i) : am0;
        m0  = fmaxf(m0, la);
        s10 = g0 ? fmaf(s10, e0, 1.0f) : (s10 + e0);
        // chain 1
        float e1 = fexp2(-fabsf(lb - m1) * KE2);
        bool  g1 = lb > m1;
        am1 = g1 ? (kbase + HALFC + i) : am1;
        m1  = fmaxf(m1, lb);
        s11 = g1 ? fmaf(s11, e1, 1.0f) : (s11 + e1);
    }
    {   // merge chains; chain0 owns lower k, so strict > keeps first max
        float em = fexp2(-fabsf(m1 - m0) * KE2);
        bool  g  = m1 > m0;
        sam[w][lane] = g ? am1 : am0;
        sm [w][lane] = fmaxf(m0, m1);
        ss1[w][lane] = g ? fmaf(s10, em, s11) : fmaf(s11, em, s10);
    }
    __syncthreads();

    // ---- flash-combine the 16 wave-chunks (every thread, own row)
    float M = sm[0][lane]; int AM = sam[0][lane];
    #pragma unroll
    for (int j = 1; j < WAVES; ++j) {
        float mj = sm[j][lane];
        if (mj > M) { M = mj; AM = sam[j][lane]; }    // ascending k: > keeps first
    }
    float S1t = 0.f;
    #pragma unroll
    for (int j = 0; j < WAVES; ++j)
        S1t += ss1[j][lane] * fexp2((sm[j][lane] - M) * KE2);
    float invS1 = 1.0f / S1t;

    // ---- pass 2: z_q_soft partials, tau-sum, entropy dot, avg_probs columns
    f32x2 vec2[8];
    #pragma unroll
    for (int q = 0; q < 8; ++q) vec2[q] = f32x2{0.f, 0.f};
    float St = 0.f, r = 0.f;
    for (int i = 0; i < CHUNK; i += 4) {
        float pv[4];
        #pragma unroll
        for (int j = 0; j < 4; ++j) {
            int ku = __builtin_amdgcn_readfirstlane(kbase + i + j);
            const f32x2* e = E + (size_t)ku * 8;
            float l  = dot16(zn2, e);
            float aa = l - M;                         // <= 0 (same dot order as pass 1)
            float aK = aa * KE2;
            float rt = fexp2(aa * KT2);               // tau weight (unnormalized)
            St += rt;
            float p  = fexp2(aK) * invS1;             // normalized ent prob
            r = fmaf(p, aK, r);                       // Σ p·a·100·log2e
            f32x2 rt2 = {rt, rt};
            #pragma unroll
            for (int q = 0; q < 8; ++q)
                vec2[q] = __builtin_elementwise_fma(rt2, e[q], vec2[q]);
            pv[j] = p;
        }
        // reduce pv[0..3] across 64 lanes: array-halving butterfly (o=2,1),
        // then single-value butterfly (o=4,8,16,32). lane l ends with k-offset l&3.
        bool u2 = (lane & 2) != 0, u1 = (lane & 1) != 0;
        float t0 = (u2 ? pv[2] : pv[0]) + __shfl_xor(u2 ? pv[0] : pv[2], 2, 64);
        float t1 = (u2 ? pv[3] : pv[1]) + __shfl_xor(u2 ? pv[1] : pv[3], 2, 64);
        float v  = (u1 ? t1 : t0) + __shfl_xor(u1 ? t0 : t1, 1, 64);
        v += __shfl_xor(v, 4, 64);
        v += __shfl_xor(v, 8, 64);
        v += __shfl_xor(v, 16, 64);
        v += __shfl_xor(v, 32, 64);
        if (lane < 4) atomicAdd(&psum[kbase + i + lane], v);
    }

    sst[w][lane] = St; sr[w][lane] = r;
    if (w >= 8) {
        #pragma unroll
        for (int q = 0; q < 8; ++q) {
            svec[w - 8][lane][2 * q]     = vec2[q].x;
            svec[w - 8][lane][2 * q + 1] = vec2[q].y;
        }
    }
    __syncthreads();
    if (w < 8) {
        #pragma unroll
        for (int q = 0; q < 8; ++q) {
            svec[w][lane][2 * q]     += vec2[q].x;
            svec[w][lane][2 * q + 1] += vec2[q].y;
        }
    }
    __syncthreads();

    // ---- epilogue (wave 0): combine + write outputs + sample-entropy
    if (w == 0) {
        float Stt = 0.f;
        #pragma unroll
        for (int j = 0; j < WAVES; ++j) Stt += sst[j][lane];
        float invSt = 1.0f / Stt;
        #pragma unroll
        for (int c = 0; c < ED; ++c) {
            float v = 0.f;
            #pragma unroll
            for (int j = 0; j < 8; ++j) v += svec[j][lane][c];
            out[OFF_SOFT + c * NPTS + n] = v * invSt;
        }
        out[OFF_IDX + n] = (float)AM;
        #pragma unroll
        for (int c = 0; c < ED; ++c)
            out[OFF_HARD + c * NPTS + n] = embN[AM * ED + c];
        // per-row sample term = ln(S1) - ln2 * Σ p·aK
        float rr = 0.f;
        #pragma unroll
        for (int j = 0; j < WAVES; ++j) rr += sr[j][lane];
        float row = logf(S1t) - LN2 * rr;
        #pragma unroll
        for (int off = 32; off > 0; off >>= 1) row += __shfl_xor(row, off, 64);
        if (lane == 0) atomicAdd(ssum, row);
    }
}

__global__ __launch_bounds__(256) void vq_finalize(const float* __restrict__ ws,
                                                   float* __restrict__ out) {
    __shared__ float red[4];
    float a = 0.f;
    for (int k = threadIdx.x; k < NE; k += 256) {
        float avg = ws[WS_PSUM + k] * (1.0f / 32768.0f);
        a += avg * logf(avg + 1e-6f);                 // = -avg_entropy contribution
    }
    #pragma unroll
    for (int off = 32; off > 0; off >>= 1) a += __shfl_xor(a, off, 64);
    if ((threadIdx.x & 63) == 0) red[threadIdx.x >> 6] = a;
    __syncthreads();
    if (threadIdx.x == 0) {
        float A = red[0] + red[1] + red[2] + red[3];  // A = -avg_entropy
        float sample = ws[WS_SSUM] * (1.0f / 32768.0f);
        out[OFF_LOSS] = 0.01f * (sample + A);         // ratio * (sample_ent - avg_ent)
    }
}

extern "C" void kernel_launch(void* const* d_in, const int* in_sizes, int n_in,
                              void* d_out, int out_size, void* d_ws, size_t ws_size,
                              hipStream_t stream) {
    const float* z   = (const float*)d_in[0];
    const float* emb = (const float*)d_in[1];
    float* out = (float*)d_out;
    float* ws  = (float*)d_ws;   // needs 34817 floats (~136 KB)

    vq_prep<<<(NE + 255) / 256, 256, 0, stream>>>(emb, ws);
    vq_main<<<NPTS / 64, WAVES * 64, 0, stream>>>(z, ws + WS_EMB, ws + WS_PSUM,
                                                  ws + WS_SSUM, out);
    vq_finalize<<<1, 256, 0, stream>>>(ws, out);
}